// Round 6
// baseline (182.026 us; speedup 1.0000x reference)
//
#include <hip/hip_runtime.h>
#include <stdint.h>

#define NB   16
#define CD   256
#define HW   1024
#define NQ   16384
#define KCN  8192

typedef unsigned long long u64;
typedef unsigned short     u16;
using f32x4  = __attribute__((ext_vector_type(4))) float;
using bf16x8 = __attribute__((ext_vector_type(8))) __bf16;

// ---------------- workspace layout (~16.9 MB) ----------------
#define ZTB_OFF  0            // u16  [NQ][CD]    8 MB  (z transposed, bf16)
#define EMBB_OFF 8388608      // u16  [KCN][CD]   4 MB  (emb, bf16)
#define EH_OFF   12582912     // f32  [KCN]      32 KB  (||e||^2/2 + 1024)
#define CAND_OFF 12615680     // u64  [NQ][32]    4 MB  (8 splits x 2 halves x top-2)

static __device__ __forceinline__ void gl_lds16(const void* g, void* l) {
  __builtin_amdgcn_global_load_lds(
      (const __attribute__((address_space(1))) void*)g,
      (__attribute__((address_space(3))) void*)l, 16, 0, 0);
}

static __device__ __forceinline__ unsigned bf16r(float x) {  // RNE fp32->bf16 bits
  unsigned u = __float_as_uint(x);
  return (u + 0x7fffu + ((u >> 16) & 1u)) >> 16;
}

static __device__ __forceinline__ u64 umin64(u64 a, u64 b) { return a < b ? a : b; }
static __device__ __forceinline__ u64 umax64(u64 a, u64 b) { return a < b ? b : a; }

// ---------------- kernel 1: merged prep (unchanged) ----------------
__global__ __launch_bounds__(256) void k_prep(const float* __restrict__ z,
                                              const float* __restrict__ emb,
                                              u16* __restrict__ zTb,
                                              u16* __restrict__ embB,
                                              float* __restrict__ eH) {
  const int bx = (int)blockIdx.x;
  if (bx < 1024) {
    __shared__ float tile[64][65];
    const int b   = bx >> 6;
    const int hwT = (bx >> 2) & 15;
    const int cT  = bx & 3;
    const int tx  = threadIdx.x & 63;
    const int ty  = threadIdx.x >> 6;
    const float* src = z + (size_t)(b * CD + cT * 64) * HW + hwT * 64;
#pragma unroll
    for (int i = 0; i < 16; ++i) {
      const int c_l = ty + 4 * i;
      tile[c_l][tx] = src[(size_t)c_l * HW + tx];
    }
    __syncthreads();
    const size_t dbase = (size_t)(b * HW + hwT * 64) * CD + cT * 64;
#pragma unroll
    for (int i = 0; i < 16; ++i) {
      const int hw_l = ty + 4 * i;
      zTb[dbase + (size_t)hw_l * CD + tx] = (u16)bf16r(tile[tx][hw_l]);
    }
  } else {
    const int wave = (bx - 1024) * 4 + ((int)threadIdx.x >> 6);  // 0..1023
    const int lane = threadIdx.x & 63;
#pragma unroll
    for (int it = 0; it < 8; ++it) {
      const int row = wave * 8 + it;
      const float4 v = *(const float4*)(emb + (size_t)row * CD + lane * 4);
      uint2 pk;
      pk.x = bf16r(v.x) | (bf16r(v.y) << 16);
      pk.y = bf16r(v.z) | (bf16r(v.w) << 16);
      *(uint2*)(embB + (size_t)row * CD + lane * 4) = pk;
      float s = v.x * v.x + v.y * v.y + v.z * v.z + v.w * v.w;
#pragma unroll
      for (int off = 32; off; off >>= 1) s += __shfl_xor(s, off, 64);
      if (lane == 0) eH[row] = 0.5f * s + 1024.0f;
    }
  }
}

// ---------------- kernel 2: R14 — 4KB chunks, ring-4, 3-deep, no lgkm drain ----
// (resubmit: round-5 bench died at container level; kernel audited — no barrier
// to deadlock on, vmcnt waits always satisfiable, all address streams in bounds)
// R13 null result: barrier-free + conflict-free + 4x less LDS read = flat 102us.
// MfmaUtil(=achieved/peak) 28.5%; plain-VALU ~12% (VALUBusy includes MFMA);
// ~56% of cycles are STALL. R13's per-chunk stall: explicit LGKM0 between the
// 8 ds_reads and all 32 MFMA serialized read-latency (~200cy dead/chunk), and
// ring-2 gave one coarse wait per 8KB. R14: chunk = 32 rows x 64 k (4KB),
// ring-4/wave (16KB, 64KB/block), prefetch 3 chunks deep. Step order:
// WAITV(counted) -> 4 ds_read -> STAGE 4 DMA (in ds-read latency shadow) ->
// 16 MFMA with compiler partial-lgkm interleave. WAR on ring slots by program
// order: slot s re-staged >=1 step after the MFMAs that consumed its reads
// (MFMA issue forces read retirement). Ledger/nt (entry [cA4,cB4,cC4,eh2]=14):
// waits 10/10/10/8; peel nt15: 10/10/6/0. Geometry/epilogue/cand = R13.

#define WAITV(N) asm volatile("s_waitcnt vmcnt(" #N ")" ::: "memory")
#define MEMFENCE() asm volatile("" ::: "memory")

__global__ __launch_bounds__(256, 2) void k_argmin(const u16* __restrict__ zTb,
                                                   const u16* __restrict__ embB,
                                                   const float* __restrict__ eH,
                                                   u64* __restrict__ cand) {
  __shared__ __align__(16) u16 Bs[4][4][2048];   // [wave][slot][4KB]

  const int tid  = (int)threadIdx.x;
  const int w    = tid >> 6;
  const int lane = tid & 63;
  const int l15  = lane & 15, quad = lane >> 4;
  const int q0    = (int)(blockIdx.x >> 3) * 128;
  const int split = (int)(blockIdx.x & 7);
  const int wq0 = (w & 1) * 64;    // q-half
  const int nh  = w >> 1;          // n-half (bucket)

  // ---- A fragments resident in registers (128 regs, 32 vmcnt entries):
  // Af[i][kq][ks][lane(quad,l15)] = A[q0+wq0+i*16+l15][kq*64+ks*32+quad*8 ..+7]
  bf16x8 Af[4][4][2];
  {
    const char* aB = (const char*)zTb + (size_t)(q0 + wq0 + l15) * 512 + quad * 16;
#pragma unroll
    for (int i = 0; i < 4; ++i)
#pragma unroll
      for (int kq = 0; kq < 4; ++kq)
#pragma unroll
        for (int ks = 0; ks < 2; ++ks)
          Af[i][kq][ks] = *(const bf16x8*)(aB + i * 8192 + kq * 128 + ks * 64);
  }
  MEMFENCE();   // A loads oldest in the wave's vmcnt queue

  // ---- wave-private ring: 4 slots x 4KB. Slot layout [n:32][slot3:8]x16B,
  // slot3 = granule ^ (n&7) (R11/R13-proven 0-conflict pattern, 128B rows).
  char* myLds = (char*)&Bs[w][0][0];
  const int lane16 = lane * 16;

  // DMA d=0..3: dest d*1024 + lane*16 -> n = d*8+(lane>>3), slot3 = lane&7;
  // global granule g = slot3 ^ (n&7) = (lane&7)^(lane>>3).
  // chunk(nt, kq) src base = bW + nt*32768 + kq*128; DMA d adds d*4096.
  const char* bW = (const char*)embB
                 + (size_t)(split * 1024 + nh * 32 + (lane >> 3)) * 512
                 + (size_t)(((lane & 7) ^ (lane >> 3)) * 16);

#define STAGE(SLOT_, SRC_)                                                     \
  do {                                                                         \
    const char* _s = (SRC_);                                                   \
    char* _d = myLds + (SLOT_) * 4096 + lane16;                                \
    gl_lds16(_s,          _d);                                                 \
    gl_lds16(_s + 4096,   _d + 1024);                                          \
    gl_lds16(_s + 8192,   _d + 2048);                                          \
    gl_lds16(_s + 12288,  _d + 3072);                                          \
    MEMFENCE();                                                                \
  } while (0)

  // frag reads: n = j*16+l15 (n&7 = l15&7 = gx), granule g = ks*4+quad at
  // slot3 = g ^ gx; addr = S*4096 + n*128 + slot3*16 ; j adds 2048.
  const int gx = l15 & 7;
  const int oA = (quad ^ gx) * 16;         // ks = 0
  const int oB = ((4 + quad) ^ gx) * 16;   // ks = 1

  f32x4 acc[4][2];
  float b1[16], b2[16];
  const float FMAX = __uint_as_float(0x7F7FFFFFu);
#pragma unroll
  for (int s = 0; s < 16; ++s) { b1[s] = FMAX; b2[s] = FMAX; }

#define ACCZERO()                                                              \
  do {                                                                         \
    _Pragma("unroll")                                                          \
    for (int i = 0; i < 4; ++i) {                                              \
      acc[i][0] = f32x4{0.f, 0.f, 0.f, 0.f};                                   \
      acc[i][1] = f32x4{0.f, 0.f, 0.f, 0.f};                                   \
    }                                                                          \
  } while (0)

// one pipeline step: 4 ds_read -> STAGECODE (DMA issue in the read-latency
// shadow) -> 16 MFMA (compiler interleaves partial lgkm waits).
#define COMPUTE(S_, KQ_, ...)                                                  \
  do {                                                                         \
    const char* _sb = myLds + (S_) * 4096 + l15 * 128;                         \
    bf16x8 f00 = *(const bf16x8*)(_sb + oA);                                   \
    bf16x8 f01 = *(const bf16x8*)(_sb + 2048 + oA);                            \
    bf16x8 f10 = *(const bf16x8*)(_sb + oB);                                   \
    bf16x8 f11 = *(const bf16x8*)(_sb + 2048 + oB);                            \
    __VA_ARGS__;                                                               \
    __builtin_amdgcn_s_setprio(1);                                             \
    _Pragma("unroll")                                                          \
    for (int i = 0; i < 4; ++i)                                                \
      acc[i][0] = __builtin_amdgcn_mfma_f32_16x16x32_bf16(Af[i][KQ_][0], f00,  \
                                                          acc[i][0], 0, 0, 0); \
    _Pragma("unroll")                                                          \
    for (int i = 0; i < 4; ++i)                                                \
      acc[i][1] = __builtin_amdgcn_mfma_f32_16x16x32_bf16(Af[i][KQ_][0], f01,  \
                                                          acc[i][1], 0, 0, 0); \
    _Pragma("unroll")                                                          \
    for (int i = 0; i < 4; ++i)                                                \
      acc[i][0] = __builtin_amdgcn_mfma_f32_16x16x32_bf16(Af[i][KQ_][1], f10,  \
                                                          acc[i][0], 0, 0, 0); \
    _Pragma("unroll")                                                          \
    for (int i = 0; i < 4; ++i)                                                \
      acc[i][1] = __builtin_amdgcn_mfma_f32_16x16x32_bf16(Af[i][KQ_][1], f11,  \
                                                          acc[i][1], 0, 0, 0); \
    __builtin_amdgcn_s_setprio(0);                                             \
  } while (0)

#define EPILOGUE(NT, EH0, EH1)                                                 \
  do {                                                                         \
    _Pragma("unroll")                                                          \
    for (int i = 0; i < 4; ++i)                                                \
      _Pragma("unroll")                                                        \
      for (int r = 0; r < 4; ++r) {                                            \
        const int s = i * 4 + r;                                               \
        const unsigned kb0 = (__float_as_uint((EH0) - acc[i][0][r]) & ~31u)    \
                             | (unsigned)((NT) * 2 + 0);                       \
        const unsigned kb1 = (__float_as_uint((EH1) - acc[i][1][r]) & ~31u)    \
                             | (unsigned)((NT) * 2 + 1);                       \
        const float k0 = __uint_as_float(kb0), k1 = __uint_as_float(kb1);      \
        const float lo = fminf(k0, k1), hi = fmaxf(k0, k1);                    \
        b2[s] = fminf(fmaxf(lo, b1[s]), fminf(hi, b2[s]));                     \
        b1[s] = fminf(lo, b1[s]);                                              \
      }                                                                        \
  } while (0)

  // ---- prologue: stage chunks (nt0,kq0..2), load eh(0).
  // queue (after A32): [c0(4), c1(4), c2(4), eh(2)] = 14
  const float* ehP = eH + split * 1024 + nh * 32 + l15;
  float ehA0, ehA1, ehN0 = 0.f, ehN1 = 0.f;

  const char* bC = bW;              // nt's src base; kq at +kq*128
  STAGE(0, bC);
  STAGE(1, bC + 128);
  STAGE(2, bC + 256);
  ehA0 = ehP[0]; ehA1 = ehP[16]; MEMFENCE();
  const float* ehN = ehP + 64;

  // ---- main loop nt = 0..14 (no barriers; per-wave counted vmcnt only)
  for (int nt = 0; nt < 15; ++nt) {
    ACCZERO();
    WAITV(10); COMPUTE(0, 0, STAGE(3, bC + 384));            // this nt, kq3
    WAITV(10); COMPUTE(1, 1, STAGE(0, bC + 32768));          // next nt, kq0
    WAITV(10); COMPUTE(2, 2, STAGE(1, bC + 32768 + 128));    // next nt, kq1
    WAITV(8);  COMPUTE(3, 3,
               { STAGE(2, bC + 32768 + 256);                 // next nt, kq2
                 ehN0 = ehN[0]; ehN1 = ehN[16]; MEMFENCE(); });
    EPILOGUE(nt, ehA0, ehA1);
    ehA0 = ehN0; ehA1 = ehN1;
    bC += 32768;
    ehN += 64;
  }

  // ---- peeled nt = 15 (stage only c63 at step0)
  {
    ACCZERO();
    WAITV(10); COMPUTE(0, 0, STAGE(3, bC + 384));
    WAITV(10); COMPUTE(1, 1, {});
    WAITV(6);  COMPUTE(2, 2, {});
    WAITV(0);  COMPUTE(3, 3, {});
    EPILOGUE(15, ehA0, ehA1);
  }
#undef STAGE
#undef COMPUTE
#undef ACCZERO
#undef EPILOGUE

  // ---- per-wave: u64 butterfly top-2 merge over 16-lane groups, write cand
#pragma unroll
  for (int s = 0; s < 16; ++s) {
    u64 x1 = ((u64)__float_as_uint(b1[s]) << 32) | (unsigned)l15;
    u64 x2 = ((u64)__float_as_uint(b2[s]) << 32) | (unsigned)l15;
#pragma unroll
    for (int off = 1; off < 16; off <<= 1) {
      const u64 o1 = __shfl_xor(x1, off, 64);
      const u64 o2 = __shfl_xor(x2, off, 64);
      const u64 lo = umin64(x1, o1);
      const u64 hi = umax64(x1, o1);
      x1 = lo;
      x2 = umin64(hi, umin64(x2, o2));
    }
    if (l15 == 0) {
      const int i = s >> 2, r = s & 3;
      const int q = q0 + wq0 + i * 16 + quad * 4 + r;
      const unsigned kb1 = (unsigned)(x1 >> 32), kb2 = (unsigned)(x2 >> 32);
      // id = nt*2 + j (5 bits): n = split*1024 + nt*64 + nh*32 + j*16 + col
      const int id1 = (int)(kb1 & 31u), id2 = (int)(kb2 & 31u);
      const int n1 = split * 1024 + (id1 >> 1) * 64 + nh * 32
                     + (id1 & 1) * 16 + (int)(x1 & 15);
      const int n2 = split * 1024 + (id2 >> 1) * 64 + nh * 32
                     + (id2 & 1) * 16 + (int)(x2 & 15);
      cand[(size_t)q * 32 + split * 4 + nh * 2 + 0] = ((u64)kb1 << 32) | (unsigned)n1;
      cand[(size_t)q * 32 + split * 4 + nh * 2 + 1] = ((u64)kb2 << 32) | (unsigned)n2;
    }
  }
}

// ---------------- kernel 3: select + fp64 rescore (native z) + output (unchanged) ----
__global__ __launch_bounds__(256) void k_pick_out(const float* __restrict__ z,
                                                  const float* __restrict__ emb,
                                                  const u64* __restrict__ cand,
                                                  float* __restrict__ out) {
  __shared__ float zs[16][257];
  __shared__ float tile[16][257];
  const int t    = (int)threadIdx.x;
  const int lane = t & 63;
  const int wv   = t >> 6;
  const int sub  = lane >> 4;
  const int l15  = lane & 15;
  const int q0b  = (int)blockIdx.x * 16;
  const int b    = q0b >> 10, hw0 = q0b & 1023;
  const int q    = q0b + wv * 4 + sub;
  const int hwl  = wv * 4 + sub;

  // ---- phase 0: stage z slice (thread t = channel)
  {
    const float* zp = z + ((size_t)(b * CD + t)) * HW + hw0;
    const float4 a0 = *(const float4*)(zp + 0);
    const float4 a1 = *(const float4*)(zp + 4);
    const float4 a2 = *(const float4*)(zp + 8);
    const float4 a3 = *(const float4*)(zp + 12);
    zs[0][t] = a0.x;  zs[1][t] = a0.y;  zs[2][t] = a0.z;  zs[3][t] = a0.w;
    zs[4][t] = a1.x;  zs[5][t] = a1.y;  zs[6][t] = a1.z;  zs[7][t] = a1.w;
    zs[8][t] = a2.x;  zs[9][t] = a2.y;  zs[10][t] = a2.z; zs[11][t] = a2.w;
    zs[12][t] = a3.x; zs[13][t] = a3.y; zs[14][t] = a3.z; zs[15][t] = a3.w;
  }
  __syncthreads();

  // ---- phase 1: top-4-of-32 select (butterfly merge of sorted-2 lists)
  const u64* cp = cand + (size_t)q * 32 + l15 * 2;
  const u64 v0 = cp[0], v1 = cp[1];
  u64 s0 = umin64(v0, v1), s1 = umax64(v0, v1), s2 = ~0ull, s3 = ~0ull;
#pragma unroll
  for (int off = 1; off < 16; off <<= 1) {
    const u64 b0 = __shfl_xor(s0, off, 64);
    const u64 b1 = __shfl_xor(s1, off, 64);
    const u64 b2 = __shfl_xor(s2, off, 64);
    const u64 b3 = __shfl_xor(s3, off, 64);
    const u64 c0 = umin64(s0, b0);
    const u64 c1 = umin64(umin64(s1, b1), umax64(s0, b0));
    const u64 c2 = umin64(umin64(s2, b2),
                          umin64(umax64(s1, b0), umax64(s0, b1)));
    const u64 c3 = umin64(umin64(umin64(s3, b3), umax64(s2, b0)),
                          umin64(umax64(s0, b2), umax64(s1, b1)));
    s0 = c0; s1 = c1; s2 = c2; s3 = c3;
  }
  const u64 sel[4] = {s0, s1, s2, s3};

  // ---- phase 2: fp64 rescore, lane handles channels c = j*16 + l15
  float zq[16];
#pragma unroll
  for (int j = 0; j < 16; ++j) zq[j] = zs[hwl][j * 16 + l15];

  double bd = 1e300;
  int bi = 0x7fffffff;
  float keep[16];
#pragma unroll
  for (int j = 0; j < 16; ++j) keep[j] = 0.f;
#pragma unroll
  for (int c4 = 0; c4 < 4; ++c4) {
    const int idx = (int)(unsigned)(sel[c4] & 0xffffffffull);
    const float* er = emb + (size_t)idx * CD;
    float ev[16];
#pragma unroll
    for (int j = 0; j < 16; ++j) ev[j] = er[j * 16 + l15];
    double s = 0.0;
#pragma unroll
    for (int j = 0; j < 16; ++j) {
      const double d = (double)zq[j] - (double)ev[j];
      s += d * d;
    }
#pragma unroll
    for (int off = 1; off < 16; off <<= 1) s += __shfl_xor(s, off, 64);
    const bool better = (s < bd) || (s == bd && idx < bi);  // uniform in 16-lane group
    if (better) {
      bd = s; bi = idx;
#pragma unroll
      for (int j = 0; j < 16; ++j) keep[j] = ev[j];
    }
  }
  // ---- phase 3: winner row -> tile, transpose-store to out
#pragma unroll
  for (int j = 0; j < 16; ++j) tile[hwl][j * 16 + l15] = keep[j];
  __syncthreads();
  const int cluster = t >> 4;   // 0..15
  const int ll      = t & 15;
  float* obase = out + (size_t)b * CD * HW + hw0 + ll;
#pragma unroll
  for (int j = 0; j < 16; ++j) {
    const int c = 16 * j + cluster;
    obase[(size_t)c * HW] = tile[ll][c];
  }
}

extern "C" void kernel_launch(void* const* d_in, const int* in_sizes, int n_in,
                              void* d_out, int out_size, void* d_ws, size_t ws_size,
                              hipStream_t stream) {
  const float* z   = (const float*)d_in[0];
  const float* emb = (const float*)d_in[1];
  float* out = (float*)d_out;

  char* ws = (char*)d_ws;
  u16*   zTb  = (u16*)(ws + ZTB_OFF);
  u16*   embB = (u16*)(ws + EMBB_OFF);
  float* eH   = (float*)(ws + EH_OFF);
  u64*   cand = (u64*)(ws + CAND_OFF);

  k_prep<<<1280, 256, 0, stream>>>(z, emb, zTb, embB, eH);
  k_argmin<<<1024, 256, 0, stream>>>(zTb, embB, eH, cand);
  k_pick_out<<<1024, 256, 0, stream>>>(z, emb, cand, out);
}